// Round 5
// baseline (219.371 us; speedup 1.0000x reference)
//
#include <hip/hip_runtime.h>
#include <math.h>

// Cross-bilateral filter, B=4, C=3, H=720, W=1280, WIN=11 (pad=5), f32.
//
// R5 design = R3's accuracy-proven DIFFERENCE-form tap math
//             + R4's structural wins (4 px/thread, f16 input, rolled wy loop).
//  - Guides (albedo rgb, depth, normal rgb) pre-scaled by sqrt(log2e/sigma),
//    packed 8 x f16 in one uint4 LDS cell (slot 8 = 0). Tap weight:
//    d = g - c (packed f16 sub), e = sum d^2 via v_dot2_f32_f16 chain,
//    w = exp2(-e). Difference form => f16 rounding error scales with |d|,
//    and large-|d| taps have negligible weight (no cancellation blowup).
//  - Input rgb packed 4 x f16 in one uint2 (b64 read).
//  - 4 vertically adjacent pixels per thread (32x32 tile): 14 window rows
//    serve 4x11 row-taps -> 77 LDS cell-reads per pixel (was 132 in R3).
//  - LDS 42x42x(16+8) = 42.3 KB -> 3 blocks/CU (12 waves/CU).

#define HH   720
#define WW   1280
#define PAD  5
#define WIN  11
#define TW   32
#define TH   32
#define HW2  42            // halo dim = TW + 2*PAD

typedef _Float16 h2 __attribute__((ext_vector_type(2)));

__device__ __forceinline__ unsigned pk2(float a, float b) {
    unsigned lo = __builtin_bit_cast(unsigned short, (_Float16)a);
    unsigned hi = __builtin_bit_cast(unsigned short, (_Float16)b);
    return lo | (hi << 16);
}

__device__ __forceinline__ float fdot2(h2 a, h2 b, float c) {
#if __has_builtin(__builtin_amdgcn_fdot2)
    return __builtin_amdgcn_fdot2(a, b, c, false);
#else
    return fmaf((float)a.x, (float)b.x, fmaf((float)a.y, (float)b.y, c));
#endif
}

__device__ __forceinline__ h2 bch2(unsigned u) { return __builtin_bit_cast(h2, u); }

__global__ __launch_bounds__(256, 3)
void xbilateral_kernel(const float* __restrict__ inp,
                       const float* __restrict__ alb,
                       const float* __restrict__ nrm,
                       const float* __restrict__ dep,
                       float* __restrict__ out)
{
    __shared__ uint4 sG[HW2][HW2];   // 8 x f16: {a0,a1,a2,dep, n0,n1,n2, 0} scaled
    __shared__ uint2 sI[HW2][HW2];   // 4 x f16: {i0,i1,i2,0}

    const int tid = threadIdx.x;
    const int lx  = tid & 31;        // 0..31
    const int ly  = tid >> 5;        // 0..7
    const int bx0 = blockIdx.x * TW;
    const int by0 = blockIdx.y * TH;
    const int b   = blockIdx.z;

    // sqrt(log2(e)/sigma): log2(e)=1.4426950408889634
    const float kA = 12.01122406f;   // sqrt(1.44269504/0.01)
    const float kN = 3.79828255f;    // sqrt(1.44269504/0.1)  (also depth)

    const size_t plane = (size_t)HH * WW;
    const float* albB = alb + (size_t)b * 3 * plane;
    const float* nrmB = nrm + (size_t)b * 3 * plane;
    const float* inpB = inp + (size_t)b * 3 * plane;
    const float* depB = dep + (size_t)b * plane;

    // ---- stage halo tile (clamped coords, scaled f16) ----
    for (int idx = tid; idx < HW2 * HW2; idx += 256) {
        int r = idx / HW2;
        int c = idx - r * HW2;
        int gy = by0 + r - PAD; gy = min(max(gy, 0), HH - 1);
        int gx = bx0 + c - PAD; gx = min(max(gx, 0), WW - 1);
        size_t o = (size_t)gy * WW + gx;
        float a0 = albB[o] * kA, a1 = albB[plane + o] * kA, a2 = albB[2 * plane + o] * kA;
        float n0 = nrmB[o] * kN, n1 = nrmB[plane + o] * kN, n2 = nrmB[2 * plane + o] * kN;
        float d0 = depB[o] * kN;
        sG[r][c] = make_uint4(pk2(a0, a1), pk2(a2, d0), pk2(n0, n1), pk2(n2, 0.f));
        float i0 = inpB[o], i1 = inpB[plane + o], i2 = inpB[2 * plane + o];
        sI[r][c] = make_uint2(pk2(i0, i1), pk2(i2, 0.f));
    }
    __syncthreads();

    // ---- per-thread: 4 vertically adjacent pixels, tile rows 4*ly + 0..3 ----
    const int py0 = 4 * ly;

    h2 c0[4], c1[4], c2[4], c3[4];
#pragma unroll
    for (int k = 0; k < 4; ++k) {
        uint4 g = sG[py0 + k + PAD][lx + PAD];
        c0[k] = bch2(g.x);
        c1[k] = bch2(g.y);
        c2[k] = bch2(g.z);
        c3[k] = bch2(g.w);
    }

    float4 acc[4];
#pragma unroll
    for (int k = 0; k < 4; ++k) acc[k] = make_float4(0.f, 0.f, 0.f, 0.f);

#pragma unroll 1
    for (int wy = 0; wy < 14; ++wy) {                  // 14 window rows
        const uint4* rg = &sG[py0 + wy][lx];
        const uint2* ri = &sI[py0 + wy][lx];
        uint4 g[WIN];
        float v0[WIN], v1[WIN], v2[WIN];
#pragma unroll
        for (int d = 0; d < WIN; ++d) g[d] = rg[d];
#pragma unroll
        for (int d = 0; d < WIN; ++d) {
            uint2 t = ri[d];
            h2 lo = bch2(t.x), hi = bch2(t.y);
            v0[d] = (float)lo.x;
            v1[d] = (float)lo.y;
            v2[d] = (float)hi.x;
        }
#pragma unroll
        for (int k = 0; k < 4; ++k) {
            if ((unsigned)(wy - k) <= 10u) {           // uniform branch: dy=wy-k in [0,10]
#pragma unroll
                for (int d = 0; d < WIN; ++d) {
                    h2 d0 = bch2(g[d].x) - c0[k];
                    h2 d1 = bch2(g[d].y) - c1[k];
                    h2 d2 = bch2(g[d].z) - c2[k];
                    h2 d3 = bch2(g[d].w) - c3[k];
                    float e = fdot2(d0, d0, fdot2(d1, d1, fdot2(d2, d2, fdot2(d3, d3, 0.f))));
                    float w = __builtin_amdgcn_exp2f(-e);
                    acc[k].x = fmaf(w, v0[d], acc[k].x);
                    acc[k].y = fmaf(w, v1[d], acc[k].y);
                    acc[k].z = fmaf(w, v2[d], acc[k].z);
                    acc[k].w += w;
                }
            }
        }
    }

    // ---- write out (guard H tail: grid y = ceil(720/32) = 23) ----
    const int ox = bx0 + lx;
    float* outB = out + (size_t)b * 3 * plane;
#pragma unroll
    for (int k = 0; k < 4; ++k) {
        int oy = by0 + py0 + k;
        if (oy < HH) {
            float inv = 1.0f / fmaxf(acc[k].w, 1e-10f);
            size_t o = (size_t)oy * WW + ox;
            outB[o]             = acc[k].x * inv;
            outB[plane + o]     = acc[k].y * inv;
            outB[2 * plane + o] = acc[k].z * inv;
        }
    }
}

extern "C" void kernel_launch(void* const* d_in, const int* in_sizes, int n_in,
                              void* d_out, int out_size, void* d_ws, size_t ws_size,
                              hipStream_t stream) {
    const float* inp = (const float*)d_in[0];
    const float* alb = (const float*)d_in[1];
    const float* nrm = (const float*)d_in[2];
    const float* dep = (const float*)d_in[3];
    // d_in[4] = win_size (always 11, compiled in)
    float* out = (float*)d_out;

    dim3 grid(WW / TW, (HH + TH - 1) / TH, 4);   // 40 x 23 x 4
    dim3 block(256);
    xbilateral_kernel<<<grid, block, 0, stream>>>(inp, alb, nrm, dep, out);
}